// Round 15
// baseline (611.581 us; speedup 1.0000x reference)
//
#include <hip/hip_runtime.h>
#include <hip/hip_bf16.h>

#define B_ 32
#define S_ 2048
#define D_ 1024
#define H_ 512
#define M_ (B_*S_)   // 65536
#define BM 128
#define BN 128
#define BK 64
#define TILE (BM*BK) // 8192 shorts = 16 KB

typedef __attribute__((ext_vector_type(8))) short short8;
typedef __attribute__((ext_vector_type(4))) float f32x4;

__device__ __forceinline__ unsigned short f2bf(float f){
  return __builtin_bit_cast(unsigned short, __float2bfloat16(f));  // RNE packed cvt
}

__device__ __forceinline__ float fast_tanh(float x){
  return 1.f - 2.f*__builtin_amdgcn_rcpf(__expf(2.f*x) + 1.f);
}

// XOR swizzle for a [128][64] bf16 LDS tile, 16B granularity (0 conflicts R4-R14).
__device__ __forceinline__ int swz(int row, int kshort){
  return row*BK + ((kshort & 56) ^ ((row&7)<<3)) + (kshort & 7);
}

// ---------------- kernel W: W1 fp32 -> bf16, tile-major PRE-SWIZZLED -------------
__global__ __launch_bounds__(256) void convw_kernel(
    const float* __restrict__ W1, unsigned short* __restrict__ W1s){
  int tid = blockIdx.x*256 + threadIdx.x;
  int n = tid*8;
  int h = n >> 10;
  int k = n & 1023;
  int bn = h >> 7, row = h & 127;
  int kt = k >> 6, kk = k & 63;
  float4 lo = *(const float4*)(W1 + n);
  float4 hi = *(const float4*)(W1 + n + 4);
  short8 r;
  r[0]=(short)f2bf(lo.x); r[1]=(short)f2bf(lo.y); r[2]=(short)f2bf(lo.z); r[3]=(short)f2bf(lo.w);
  r[4]=(short)f2bf(hi.x); r[5]=(short)f2bf(hi.y); r[6]=(short)f2bf(hi.z); r[7]=(short)f2bf(hi.w);
  *(short8*)&W1s[(bn*16 + kt)*TILE + swz(row, kk)] = r;
}

// ---------------- kernel 0: qbias (R1 form — measured 9.9 us) --------------------
__global__ __launch_bounds__(256) void qbias_kernel(
    const float* __restrict__ hidden, const float* __restrict__ W2,
    const float* __restrict__ W1b, const float* __restrict__ W2b,
    float* __restrict__ qb){
  int b = blockIdx.x, h0 = blockIdx.y*64;
  int wave = threadIdx.x>>6, lane = threadIdx.x&63;
  const float* q = hidden + (size_t)(B_ + b)*D_;   // hidden[-1]
  for (int i=0;i<16;i++){
    int h = h0 + wave*16 + i;
    const float* w = W2 + (size_t)h*D_;
    float s = 0.f;
    #pragma unroll
    for (int it=0; it<4; ++it){
      int d = it*256 + lane*4;
      const float4 qq = *(const float4*)(q+d);
      const float4 ww = *(const float4*)(w+d);
      s += qq.x*ww.x + qq.y*ww.y + qq.z*ww.z + qq.w*ww.w;
    }
    #pragma unroll
    for (int off=1; off<64; off<<=1) s += __shfl_xor(s, off);
    if (lane==0) qb[b*H_ + h] = s + W1b[h] + W2b[h];
  }
}

// ---------------- kernel 1: fused score GEMM — 2-step A runway, STATIC buffers ---
// Steady step kt (in-flight on entry: B(kt+1):4, A(kt+1):8, A(kt+2):8):
//   COMPUTE(Bs[kt&1]) | bar | GLD_B(kt+2) | CVT_A(kt+1) [auto vmcnt(16)]
//   | LOAD_A(kt+3) | vmcnt(20)+lgkm(0) [drains B(kt+1) only] | bar
// Manual 2-step unroll -> all reg-buffer selectors compile-time (no spill; R14 lesson).
__global__ __launch_bounds__(256, 3) void score_gemm(
    const float* __restrict__ enc, const unsigned short* __restrict__ W1s,
    const float* __restrict__ qb, const float* __restrict__ Vw,
    float* __restrict__ score_p){
  const int id  = blockIdx.x;
  const int xcd = id & 7;
  const int j   = id >> 3;
  const int bm  = xcd*64 + (j >> 2);    // 4 same-bm blocks on same XCD (R5)
  const int bn  = j & 3;
  const int m0 = bm*BM, h0 = bn*BN;
  const int tid = threadIdx.x, lane = tid&63, wave = tid>>6;
  const int wm = (wave>>1)*64, wn = (wave&1)*64;

  __shared__ __align__(16) unsigned short As[TILE];      // 16 KB
  __shared__ __align__(16) unsigned short Bs[2][TILE];   // 32 KB

  f32x4 acc[4][4];
  #pragma unroll
  for (int i=0;i<4;i++)
    #pragma unroll
    for (int j2=0;j2<4;j2++)
      acc[i][j2] = (f32x4)(0.f);

  float4 aLo0[4], aHi0[4], aLo1[4], aHi1[4];   // A(even)->buf0, A(odd)->buf1

#define LOAD_A0(KT) do{ const int kkx=(KT)*BK; \
  _Pragma("unroll") for (int i=0;i<4;i++){ \
    int c=tid+i*256; int row=c>>3, kc=(c&7)*8; \
    const float4* pa=(const float4*)(enc+(size_t)(m0+row)*D_+kkx+kc); \
    aLo0[i]=pa[0]; aHi0[i]=pa[1]; } }while(0)
#define LOAD_A1(KT) do{ const int kkx=(KT)*BK; \
  _Pragma("unroll") for (int i=0;i<4;i++){ \
    int c=tid+i*256; int row=c>>3, kc=(c&7)*8; \
    const float4* pa=(const float4*)(enc+(size_t)(m0+row)*D_+kkx+kc); \
    aLo1[i]=pa[0]; aHi1[i]=pa[1]; } }while(0)

#define GLD_B(KT,P) do{ const unsigned short* bsrc=W1s+(size_t)(bn*16+(KT))*TILE; \
  _Pragma("unroll") for (int i=0;i<4;i++){ \
    __builtin_amdgcn_global_load_lds( \
      (const __attribute__((address_space(1))) unsigned int*)(bsrc+i*2048+tid*8), \
      (__attribute__((address_space(3))) unsigned int*)&Bs[P][i*2048+tid*8], 16,0,0); } }while(0)

#define CVT_A0() do{ \
  _Pragma("unroll") for (int i=0;i<4;i++){ \
    int c=tid+i*256; int row=c>>3, kc=(c&7)*8; short8 av; \
    av[0]=(short)f2bf(aLo0[i].x); av[1]=(short)f2bf(aLo0[i].y); \
    av[2]=(short)f2bf(aLo0[i].z); av[3]=(short)f2bf(aLo0[i].w); \
    av[4]=(short)f2bf(aHi0[i].x); av[5]=(short)f2bf(aHi0[i].y); \
    av[6]=(short)f2bf(aHi0[i].z); av[7]=(short)f2bf(aHi0[i].w); \
    *(short8*)&As[swz(row,kc)] = av; } }while(0)
#define CVT_A1() do{ \
  _Pragma("unroll") for (int i=0;i<4;i++){ \
    int c=tid+i*256; int row=c>>3, kc=(c&7)*8; short8 av; \
    av[0]=(short)f2bf(aLo1[i].x); av[1]=(short)f2bf(aLo1[i].y); \
    av[2]=(short)f2bf(aLo1[i].z); av[3]=(short)f2bf(aLo1[i].w); \
    av[4]=(short)f2bf(aHi1[i].x); av[5]=(short)f2bf(aHi1[i].y); \
    av[6]=(short)f2bf(aHi1[i].z); av[7]=(short)f2bf(aHi1[i].w); \
    *(short8*)&As[swz(row,kc)] = av; } }while(0)

#define COMPUTE(P) do{ \
  _Pragma("unroll") for (int kh=0; kh<2; ++kh){ \
    const int kb = kh*32 + (lane>>4)*8; \
    short8 af[4], bf[4]; \
    _Pragma("unroll") for (int mi=0;mi<4;mi++){ \
      int row=wm+mi*16+(lane&15); af[mi]=*(const short8*)&As[swz(row,kb)]; } \
    _Pragma("unroll") for (int ni=0;ni<4;ni++){ \
      int row=wn+ni*16+(lane&15); bf[ni]=*(const short8*)&Bs[P][swz(row,kb)]; } \
    _Pragma("unroll") for (int mi=0;mi<4;mi++) \
      _Pragma("unroll") for (int ni=0;ni<4;ni++) \
        acc[mi][ni]=__builtin_amdgcn_mfma_f32_16x16x32_bf16(af[mi],bf[ni],acc[mi][ni],0,0,0); \
  } }while(0)

#define SB() __builtin_amdgcn_sched_barrier(0)
#define WAITV(N) asm volatile("s_waitcnt vmcnt(" #N ") lgkmcnt(0)" ::: "memory")

  // ---- prologue.  FIFO: B0, A0, B1, A1, [CVT_A0 drains <=A0], A2
  GLD_B(0,0);  SB();
  LOAD_A0(0);  SB();
  GLD_B(1,1);  SB();
  LOAD_A1(1);  SB();
  CVT_A0();                       // auto-wait A0 -> drains B0 too
  LOAD_A0(2);  SB();              // in flight: B1(4), A1(8), A2(8)
  asm volatile("s_waitcnt lgkmcnt(0)" ::: "memory");
  __builtin_amdgcn_s_barrier();

  // ---- steady: 6 pairs, kt = 0..11 — all buffer selectors static
  for (int t=0; t<6; ++t){
    const int kt = 2*t;
    // even step kt: Bs0=B(kt); consume A-buf1=A(kt+1); refill buf1 with A(kt+3)
    COMPUTE(0);
    __builtin_amdgcn_s_barrier();
    GLD_B(kt+2, 0);  SB();
    CVT_A1();                     // A(kt+1), loaded 2 steps ago; auto vmcnt(16)
    LOAD_A1(kt+3);   SB();
    WAITV(20);                    // drain B(kt+1); keep A(kt+2),B(kt+2),A(kt+3)
    __builtin_amdgcn_s_barrier();
    // odd step kt+1: Bs1=B(kt+1); consume buf0=A(kt+2); refill buf0 with A(kt+4)
    COMPUTE(1);
    __builtin_amdgcn_s_barrier();
    GLD_B(kt+3, 1);  SB();
    CVT_A0();                     // A(kt+2)
    LOAD_A0(kt+4);   SB();
    WAITV(20);                    // drain B(kt+2)
    __builtin_amdgcn_s_barrier();
  }
  // ---- kt=12 (even). entry in-flight: B13:4, A13:8, A14:8
  COMPUTE(0);
  __builtin_amdgcn_s_barrier();
  GLD_B(14, 0);  SB();
  CVT_A1();                       // A13 (auto vmcnt(16))
  LOAD_A1(15);   SB();
  WAITV(20);                      // drain B13; keep A14,B14,A15
  __builtin_amdgcn_s_barrier();
  // ---- kt=13 (odd). in-flight: B14:4, A14:8, A15:8
  COMPUTE(1);
  __builtin_amdgcn_s_barrier();
  GLD_B(15, 1);  SB();
  CVT_A0();                       // A14 (auto vmcnt(16): leaves B14,A15,B15)
  SB();
  WAITV(12);                      // drain B14; keep A15:8,B15:4
  __builtin_amdgcn_s_barrier();
  // ---- kt=14 (even). in-flight: A15:8, B15:4
  COMPUTE(0);
  __builtin_amdgcn_s_barrier();
  CVT_A1();                       // A15 (auto vmcnt(4): leaves B15)
  SB();
  WAITV(0);                       // B15 done
  __builtin_amdgcn_s_barrier();
  // ---- kt=15
  COMPUTE(1);

  // ---- epilogue: fast-tanh + V_w reduce -> per-bn partial score ----------------
  const int bidx = m0 >> 11;
  float qv[4], vwv[4];
  #pragma unroll
  for (int ni=0;ni<4;ni++){
    int h = h0 + wn + ni*16 + (lane&15);
    qv[ni]  = qb[bidx*H_ + h];
    vwv[ni] = Vw[h];
  }
  __shared__ float psum[4][BM];
  #pragma unroll
  for (int mi=0;mi<4;mi++){
    #pragma unroll
    for (int r=0;r<4;r++){
      float s = 0.f;
      #pragma unroll
      for (int ni=0;ni<4;ni++) s += fast_tanh(acc[mi][ni][r] + qv[ni]) * vwv[ni];
      s += __shfl_xor(s,1); s += __shfl_xor(s,2);
      s += __shfl_xor(s,4); s += __shfl_xor(s,8);
      if ((lane&15)==0){
        int m = wm + mi*16 + ((lane>>4)<<2) + r;
        psum[wave][m] = s;
      }
    }
  }
  __syncthreads();
  if (tid < BM){
    int w0 = (tid>>6)*2;
    score_p[(size_t)bn*M_ + m0 + tid] = psum[w0][tid] + psum[w0+1][tid];
  }
}

// ---------------- kernel 2: masked softmax over S (sums 4 bn partials) -----------
__global__ __launch_bounds__(256) void softmax_kernel(
    const float* __restrict__ score_p, const int* __restrict__ mask,
    float* __restrict__ attn){
  int b = blockIdx.x, tid = threadIdx.x;
  int wave = tid>>6, lane = tid&63;
  __shared__ float red[8];
  float v[8];
  float mx = -1e30f;
  #pragma unroll
  for (int i=0;i<8;i++){
    int idx = b*S_ + tid + i*256;
    float sc = score_p[idx] + score_p[M_+idx] + score_p[2*M_+idx] + score_p[3*M_+idx];
    v[i] = (mask[idx]==0) ? -1e9f : sc;
    mx = fmaxf(mx, v[i]);
  }
  #pragma unroll
  for (int off=1; off<64; off<<=1) mx = fmaxf(mx, __shfl_xor(mx, off));
  if (lane==0) red[wave] = mx;
  __syncthreads();
  mx = fmaxf(fmaxf(red[0],red[1]), fmaxf(red[2],red[3]));
  float sum = 0.f;
  #pragma unroll
  for (int i=0;i<8;i++){ v[i] = __expf(v[i]-mx); sum += v[i]; }
  #pragma unroll
  for (int off=1; off<64; off<<=1) sum += __shfl_xor(sum, off);
  if (lane==0) red[4+wave] = sum;
  __syncthreads();
  float inv = 1.f/(red[4]+red[5]+red[6]+red[7]);
  #pragma unroll
  for (int i=0;i<8;i++) attn[b*S_ + tid + i*256] = v[i]*inv;
}

// ---------------- kernel 3a: context partials (NO atomics, streaming stores) -----
__global__ __launch_bounds__(256) void context_part(
    const float* __restrict__ enc, const float* __restrict__ attn,
    float* __restrict__ ctx_p){
  int b = blockIdx.x, sc = blockIdx.y;        // 32 s-chunks of 64 rows
  int s0 = sc*64;
  int d4 = threadIdx.x*4;
  const float* ep = enc + ((size_t)b*S_ + s0)*D_ + d4;
  const float* ap = attn + b*S_ + s0;
  float4 a0 = make_float4(0.f,0.f,0.f,0.f);
  float4 a1 = make_float4(0.f,0.f,0.f,0.f);
  #pragma unroll 4
  for (int i=0;i<64;i+=2){
    float w0 = ap[i], w1 = ap[i+1];
    float4 e0 = *(const float4*)(ep + (size_t)i*D_);
    float4 e1 = *(const float4*)(ep + (size_t)(i+1)*D_);
    a0.x = fmaf(w0, e0.x, a0.x); a0.y = fmaf(w0, e0.y, a0.y);
    a0.z = fmaf(w0, e0.z, a0.z); a0.w = fmaf(w0, e0.w, a0.w);
    a1.x = fmaf(w1, e1.x, a1.x); a1.y = fmaf(w1, e1.y, a1.y);
    a1.z = fmaf(w1, e1.z, a1.z); a1.w = fmaf(w1, e1.w, a1.w);
  }
  float4 t = make_float4(a0.x+a1.x, a0.y+a1.y, a0.z+a1.z, a0.w+a1.w);
  *(float4*)(ctx_p + ((size_t)b*32 + sc)*D_ + d4) = t;
}

// ---------------- kernel 3b: reduce 32 partials -> ctx ---------------------------
__global__ __launch_bounds__(256) void context_reduce(
    const float* __restrict__ ctx_p, float* __restrict__ ctx){
  int b = blockIdx.x;
  int d4 = threadIdx.x*4;
  f32x4 s = (f32x4)(0.f);
  #pragma unroll 8
  for (int sc=0; sc<32; ++sc)
    s += *(const f32x4*)(ctx_p + ((size_t)b*32 + sc)*D_ + d4);
  *(f32x4*)(ctx + (size_t)b*D_ + d4) = s;
}

extern "C" void kernel_launch(void* const* d_in, const int* in_sizes, int n_in,
                              void* d_out, int out_size, void* d_ws, size_t ws_size,
                              hipStream_t stream){
  const float* hidden = (const float*)d_in[0];
  const float* enc    = (const float*)d_in[1];
  const int*   mask   = (const int*)d_in[2];
  const float* W1w    = (const float*)d_in[3];
  const float* W1b    = (const float*)d_in[4];
  const float* W2w    = (const float*)d_in[5];
  const float* W2b    = (const float*)d_in[6];
  const float* Vw     = (const float*)d_in[7];
  // V_b (d_in[8]) provably cancels in softmax — unused.
  float* out = (float*)d_out;

  float* qb           = (float*)d_ws;                      // 64 KB
  float* score_p      = qb + B_*H_;                        // 4*M_ f32 = 1 MB
  unsigned short* W1s = (unsigned short*)(score_p + 4*M_); // 1 MB bf16 pre-swizzled
  float* ctx_p        = (float*)(W1s + H_*D_);             // 4 MB

  convw_kernel  <<<H_*D_/8/256,     256, 0, stream>>>(W1w, W1s);
  qbias_kernel  <<<dim3(B_, H_/64), 256, 0, stream>>>(hidden, W2w, W1b, W2b, qb);
  score_gemm    <<<4*(M_/BM),       256, 0, stream>>>(enc, W1s, qb, Vw, score_p);
  softmax_kernel<<<B_,              256, 0, stream>>>(score_p, mask, out + B_*D_);
  context_part  <<<dim3(B_, 32),    256, 0, stream>>>(enc, out + B_*D_, ctx_p);
  context_reduce<<<B_,              256, 0, stream>>>(ctx_p, out);
}

// Round 19
// 179.887 us; speedup vs baseline: 3.3998x; 3.3998x over previous
//
#include <hip/hip_runtime.h>
#include <hip/hip_bf16.h>

#define B_ 32
#define S_ 2048
#define D_ 1024
#define H_ 512
#define M_ (B_*S_)   // 65536
#define BM 64
#define BN 128
#define BK 64
#define TILE_A (BM*BK)   // 4096 shorts = 8 KB
#define TILE_B (BN*BK)   // 8192 shorts = 16 KB

typedef __attribute__((ext_vector_type(8))) short short8;
typedef __attribute__((ext_vector_type(4))) float f32x4;

__device__ __forceinline__ unsigned short f2bf(float f){
  return __builtin_bit_cast(unsigned short, __float2bfloat16(f));  // RNE packed cvt
}

__device__ __forceinline__ float fast_tanh(float x){
  return 1.f - 2.f*__builtin_amdgcn_rcpf(__expf(2.f*x) + 1.f);
}

// XOR swizzle for [rows][64] bf16 LDS tiles, 16B granularity (0 conflicts R4-R15).
__device__ __forceinline__ int swz(int row, int kshort){
  return row*BK + ((kshort & 56) ^ ((row&7)<<3)) + (kshort & 7);
}

// ---------------- kernel W: W1 fp32 -> bf16, tile-major PRE-SWIZZLED -------------
// Same layout as R7/R12 (BN=128 rows per tile): tile index (bn*16+kt), rows 0..127.
__global__ __launch_bounds__(256) void convw_kernel(
    const float* __restrict__ W1, unsigned short* __restrict__ W1s){
  int tid = blockIdx.x*256 + threadIdx.x;
  int n = tid*8;
  int h = n >> 10;
  int k = n & 1023;
  int bn = h >> 7, row = h & 127;
  int kt = k >> 6, kk = k & 63;
  float4 lo = *(const float4*)(W1 + n);
  float4 hi = *(const float4*)(W1 + n + 4);
  short8 r;
  r[0]=(short)f2bf(lo.x); r[1]=(short)f2bf(lo.y); r[2]=(short)f2bf(lo.z); r[3]=(short)f2bf(lo.w);
  r[4]=(short)f2bf(hi.x); r[5]=(short)f2bf(hi.y); r[6]=(short)f2bf(hi.z); r[7]=(short)f2bf(hi.w);
  *(short8*)&W1s[(bn*16 + kt)*TILE_B + swz(row, kk)] = r;
}

// ---------------- kernel 0: qbias (R1 form — measured 9.9 us) --------------------
__global__ __launch_bounds__(256) void qbias_kernel(
    const float* __restrict__ hidden, const float* __restrict__ W2,
    const float* __restrict__ W1b, const float* __restrict__ W2b,
    float* __restrict__ qb){
  int b = blockIdx.x, h0 = blockIdx.y*64;
  int wave = threadIdx.x>>6, lane = threadIdx.x&63;
  const float* q = hidden + (size_t)(B_ + b)*D_;   // hidden[-1]
  for (int i=0;i<16;i++){
    int h = h0 + wave*16 + i;
    const float* w = W2 + (size_t)h*D_;
    float s = 0.f;
    #pragma unroll
    for (int it=0; it<4; ++it){
      int d = it*256 + lane*4;
      const float4 qq = *(const float4*)(q+d);
      const float4 ww = *(const float4*)(w+d);
      s += qq.x*ww.x + qq.y*ww.y + qq.z*ww.z + qq.w*ww.w;
    }
    #pragma unroll
    for (int off=1; off<64; off<<=1) s += __shfl_xor(s, off);
    if (lane==0) qb[b*H_ + h] = s + W1b[h] + W2b[h];
  }
}

// ---------------- kernel 1: fused score GEMM — BM=64, 4 blocks/CU ----------------
// R7 schedule verbatim; smaller tile raises occupancy 31->~48% (latency-bound fix).
// Wave-tile 64x32: af[4] x bf[2] x 2kh = 16 MFMA/wave/step.
__global__ __launch_bounds__(256, 4) void score_gemm(
    const float* __restrict__ enc, const unsigned short* __restrict__ W1s,
    const float* __restrict__ qb, const float* __restrict__ Vw,
    float* __restrict__ score_p){
  const int id  = blockIdx.x;
  const int xcd = id & 7;
  const int j   = id >> 3;                // 0..511
  const int bm  = xcd*128 + (j >> 2);     // 0..1023; 4 same-bm blocks on same XCD
  const int bn  = j & 3;
  const int m0 = bm*BM, h0 = bn*BN;
  const int tid = threadIdx.x, lane = tid&63, wave = tid>>6;
  const int wn = wave*32;                 // wave's h offset within tile

  __shared__ __align__(16) unsigned short As[TILE_A];      //  8 KB
  __shared__ __align__(16) unsigned short Bs[2][TILE_B];   // 32 KB

  f32x4 acc[4][2];
  #pragma unroll
  for (int i=0;i<4;i++)
    #pragma unroll
    for (int j2=0;j2<2;j2++)
      acc[i][j2] = (f32x4)(0.f);

  float4 aLo[2], aHi[2];   // A staging: 64x64 fp32 = 16 elems/thread

#define LOAD_A(KT) do{ const int kkx=(KT)*BK; \
  _Pragma("unroll") for (int i=0;i<2;i++){ \
    int c=tid+i*256; int row=c>>3, kc=(c&7)*8; \
    const float4* pa=(const float4*)(enc+(size_t)(m0+row)*D_+kkx+kc); \
    aLo[i]=pa[0]; aHi[i]=pa[1]; } }while(0)

#define GLD_B(KT,P) do{ const unsigned short* bsrc=W1s+(size_t)(bn*16+(KT))*TILE_B; \
  _Pragma("unroll") for (int i=0;i<4;i++){ \
    __builtin_amdgcn_global_load_lds( \
      (const __attribute__((address_space(1))) unsigned int*)(bsrc+i*2048+tid*8), \
      (__attribute__((address_space(3))) unsigned int*)&Bs[P][i*2048+tid*8], 16,0,0); } }while(0)

#define CVT_A() do{ \
  _Pragma("unroll") for (int i=0;i<2;i++){ \
    int c=tid+i*256; int row=c>>3, kc=(c&7)*8; short8 av; \
    av[0]=(short)f2bf(aLo[i].x); av[1]=(short)f2bf(aLo[i].y); \
    av[2]=(short)f2bf(aLo[i].z); av[3]=(short)f2bf(aLo[i].w); \
    av[4]=(short)f2bf(aHi[i].x); av[5]=(short)f2bf(aHi[i].y); \
    av[6]=(short)f2bf(aHi[i].z); av[7]=(short)f2bf(aHi[i].w); \
    *(short8*)&As[swz(row,kc)] = av; } }while(0)

#define COMPUTE(P) do{ \
  _Pragma("unroll") for (int kh=0; kh<2; ++kh){ \
    const int kb = kh*32 + (lane>>4)*8; \
    short8 af[4], bf[2]; \
    _Pragma("unroll") for (int mi=0;mi<4;mi++){ \
      int row=mi*16+(lane&15); af[mi]=*(const short8*)&As[swz(row,kb)]; } \
    _Pragma("unroll") for (int ni=0;ni<2;ni++){ \
      int row=wn+ni*16+(lane&15); bf[ni]=*(const short8*)&Bs[P][swz(row,kb)]; } \
    _Pragma("unroll") for (int mi=0;mi<4;mi++) \
      _Pragma("unroll") for (int ni=0;ni<2;ni++) \
        acc[mi][ni]=__builtin_amdgcn_mfma_f32_16x16x32_bf16(af[mi],bf[ni],acc[mi][ni],0,0,0); \
  } }while(0)

  // ---- prologue: As=A0, Bs[0]=B0 (drained), A1+B1 in flight
  LOAD_A(0);                                   // A0:4
  GLD_B(0,0);                                  // B0:4
  CVT_A();                                     // auto-wait A0 (leaves B0)
  LOAD_A(1);                                   // A1:4
  GLD_B(1,1);                                  // B1:4
  asm volatile("s_waitcnt vmcnt(8) lgkmcnt(0)" ::: "memory");  // drain B0; keep A1,B1
  __builtin_amdgcn_s_barrier();

  // ---- steady: kt = 0..13
  #pragma unroll 2
  for (int kt=0; kt<14; ++kt){
    const int p = kt&1;
    COMPUTE(p);                                // As(kt), Bs[p]=B(kt)
    __builtin_amdgcn_s_barrier();              // all reads of As/Bs[p] done
    GLD_B(kt+2, p);                            // refill just-freed Bs[p]
    CVT_A();                                   // auto-wait A(kt+1) -> drains B(kt+1) too
    LOAD_A(kt+2);
    asm volatile("s_waitcnt lgkmcnt(0)" ::: "memory");  // As writes visible
    __builtin_amdgcn_s_barrier();
  }
  // ---- tail kt=14
  COMPUTE(0);                                  // As(14), Bs[0]=B14
  __builtin_amdgcn_s_barrier();
  CVT_A();                                     // waits A15 -> drains B15 too
  asm volatile("s_waitcnt lgkmcnt(0)" ::: "memory");
  __builtin_amdgcn_s_barrier();
  // ---- tail kt=15
  COMPUTE(1);                                  // As(15), Bs[1]=B15

  // ---- epilogue: fast-tanh + V_w reduce -> per-bn partial score ----------------
  const int bidx = m0 >> 11;                   // batch (64 | 2048)
  float qv[2], vwv[2];
  #pragma unroll
  for (int ni=0;ni<2;ni++){
    int h = h0 + wn + ni*16 + (lane&15);
    qv[ni]  = qb[bidx*H_ + h];
    vwv[ni] = Vw[h];
  }
  float* psum = (float*)As;                    // alias: As free after K-loop (4*64 f32 = 1KB)
  __builtin_amdgcn_s_barrier();                // all As reads done before overwrite
  #pragma unroll
  for (int mi=0;mi<4;mi++){
    #pragma unroll
    for (int r=0;r<4;r++){
      float s = 0.f;
      #pragma unroll
      for (int ni=0;ni<2;ni++) s += fast_tanh(acc[mi][ni][r] + qv[ni]) * vwv[ni];
      s += __shfl_xor(s,1); s += __shfl_xor(s,2);
      s += __shfl_xor(s,4); s += __shfl_xor(s,8);
      if ((lane&15)==0){
        int m = mi*16 + ((lane>>4)<<2) + r;     // 0..63
        psum[wave*BM + m] = s;
      }
    }
  }
  __syncthreads();
  if (tid < BM)
    score_p[(size_t)bn*M_ + m0 + tid] =
      psum[tid] + psum[BM+tid] + psum[2*BM+tid] + psum[3*BM+tid];
}

// ---------------- kernel 2: masked softmax over S (sums 4 bn partials) -----------
__global__ __launch_bounds__(256) void softmax_kernel(
    const float* __restrict__ score_p, const int* __restrict__ mask,
    float* __restrict__ attn){
  int b = blockIdx.x, tid = threadIdx.x;
  int wave = tid>>6, lane = tid&63;
  __shared__ float red[8];
  float v[8];
  float mx = -1e30f;
  #pragma unroll
  for (int i=0;i<8;i++){
    int idx = b*S_ + tid + i*256;
    float sc = score_p[idx] + score_p[M_+idx] + score_p[2*M_+idx] + score_p[3*M_+idx];
    v[i] = (mask[idx]==0) ? -1e9f : sc;
    mx = fmaxf(mx, v[i]);
  }
  #pragma unroll
  for (int off=1; off<64; off<<=1) mx = fmaxf(mx, __shfl_xor(mx, off));
  if (lane==0) red[wave] = mx;
  __syncthreads();
  mx = fmaxf(fmaxf(red[0],red[1]), fmaxf(red[2],red[3]));
  float sum = 0.f;
  #pragma unroll
  for (int i=0;i<8;i++){ v[i] = __expf(v[i]-mx); sum += v[i]; }
  #pragma unroll
  for (int off=1; off<64; off<<=1) sum += __shfl_xor(sum, off);
  if (lane==0) red[4+wave] = sum;
  __syncthreads();
  float inv = 1.f/(red[4]+red[5]+red[6]+red[7]);
  #pragma unroll
  for (int i=0;i<8;i++) attn[b*S_ + tid + i*256] = v[i]*inv;
}

// ---------------- kernel 3a: context partials (NO atomics, streaming stores) -----
__global__ __launch_bounds__(256) void context_part(
    const float* __restrict__ enc, const float* __restrict__ attn,
    float* __restrict__ ctx_p){
  int b = blockIdx.x, sc = blockIdx.y;        // 32 s-chunks of 64 rows
  int s0 = sc*64;
  int d4 = threadIdx.x*4;
  const float* ep = enc + ((size_t)b*S_ + s0)*D_ + d4;
  const float* ap = attn + b*S_ + s0;
  float4 a0 = make_float4(0.f,0.f,0.f,0.f);
  float4 a1 = make_float4(0.f,0.f,0.f,0.f);
  #pragma unroll 4
  for (int i=0;i<64;i+=2){
    float w0 = ap[i], w1 = ap[i+1];
    float4 e0 = *(const float4*)(ep + (size_t)i*D_);
    float4 e1 = *(const float4*)(ep + (size_t)(i+1)*D_);
    a0.x = fmaf(w0, e0.x, a0.x); a0.y = fmaf(w0, e0.y, a0.y);
    a0.z = fmaf(w0, e0.z, a0.z); a0.w = fmaf(w0, e0.w, a0.w);
    a1.x = fmaf(w1, e1.x, a1.x); a1.y = fmaf(w1, e1.y, a1.y);
    a1.z = fmaf(w1, e1.z, a1.z); a1.w = fmaf(w1, e1.w, a1.w);
  }
  float4 t = make_float4(a0.x+a1.x, a0.y+a1.y, a0.z+a1.z, a0.w+a1.w);
  *(float4*)(ctx_p + ((size_t)b*32 + sc)*D_ + d4) = t;
}

// ---------------- kernel 3b: reduce 32 partials -> ctx ---------------------------
__global__ __launch_bounds__(256) void context_reduce(
    const float* __restrict__ ctx_p, float* __restrict__ ctx){
  int b = blockIdx.x;
  int d4 = threadIdx.x*4;
  f32x4 s = (f32x4)(0.f);
  #pragma unroll 8
  for (int sc=0; sc<32; ++sc)
    s += *(const f32x4*)(ctx_p + ((size_t)b*32 + sc)*D_ + d4);
  *(f32x4*)(ctx + (size_t)b*D_ + d4) = s;
}

extern "C" void kernel_launch(void* const* d_in, const int* in_sizes, int n_in,
                              void* d_out, int out_size, void* d_ws, size_t ws_size,
                              hipStream_t stream){
  const float* hidden = (const float*)d_in[0];
  const float* enc    = (const float*)d_in[1];
  const int*   mask   = (const int*)d_in[2];
  const float* W1w    = (const float*)d_in[3];
  const float* W1b    = (const float*)d_in[4];
  const float* W2w    = (const float*)d_in[5];
  const float* W2b    = (const float*)d_in[6];
  const float* Vw     = (const float*)d_in[7];
  // V_b (d_in[8]) provably cancels in softmax — unused.
  float* out = (float*)d_out;

  float* qb           = (float*)d_ws;                      // 64 KB
  float* score_p      = qb + B_*H_;                        // 4*M_ f32 = 1 MB
  unsigned short* W1s = (unsigned short*)(score_p + 4*M_); // 1 MB bf16 pre-swizzled
  float* ctx_p        = (float*)(W1s + H_*D_);             // 4 MB

  convw_kernel  <<<H_*D_/8/256,     256, 0, stream>>>(W1w, W1s);
  qbias_kernel  <<<dim3(B_, H_/64), 256, 0, stream>>>(hidden, W2w, W1b, W2b, qb);
  score_gemm    <<<4*(M_/BM),       256, 0, stream>>>(enc, W1s, qb, Vw, score_p);
  softmax_kernel<<<B_,              256, 0, stream>>>(score_p, mask, out + B_*D_);
  context_part  <<<dim3(B_, 32),    256, 0, stream>>>(enc, out + B_*D_, ctx_p);
  context_reduce<<<B_,              256, 0, stream>>>(ctx_p, out);
}

// Round 22
// 169.775 us; speedup vs baseline: 3.6023x; 1.0596x over previous
//
#include <hip/hip_runtime.h>
#include <hip/hip_bf16.h>

#define B_ 32
#define S_ 2048
#define D_ 1024
#define H_ 512
#define M_ (B_*S_)   // 65536
#define BM 128
#define BN 128
#define BK 64
#define TILE (BM*BK) // 8192 shorts = 16 KB

typedef __attribute__((ext_vector_type(8))) short short8;
typedef __attribute__((ext_vector_type(4))) float f32x4;

__device__ __forceinline__ unsigned short f2bf(float f){
  return __builtin_bit_cast(unsigned short, __float2bfloat16(f));  // RNE packed cvt
}

__device__ __forceinline__ float fast_tanh(float x){
  return 1.f - 2.f*__builtin_amdgcn_rcpf(__expf(2.f*x) + 1.f);
}

// XOR swizzle for a [128][64] bf16 LDS tile, 16B granularity (0 conflicts R4-R19).
__device__ __forceinline__ int swz(int row, int kshort){
  return row*BK + ((kshort & 56) ^ ((row&7)<<3)) + (kshort & 7);
}

// ---------------- kernel W: W1 fp32 -> bf16, tile-major PRE-SWIZZLED -------------
__global__ __launch_bounds__(256) void convw_kernel(
    const float* __restrict__ W1, unsigned short* __restrict__ W1s){
  int tid = blockIdx.x*256 + threadIdx.x;
  int n = tid*8;
  int h = n >> 10;
  int k = n & 1023;
  int bn = h >> 7, row = h & 127;
  int kt = k >> 6, kk = k & 63;
  float4 lo = *(const float4*)(W1 + n);
  float4 hi = *(const float4*)(W1 + n + 4);
  short8 r;
  r[0]=(short)f2bf(lo.x); r[1]=(short)f2bf(lo.y); r[2]=(short)f2bf(lo.z); r[3]=(short)f2bf(lo.w);
  r[4]=(short)f2bf(hi.x); r[5]=(short)f2bf(hi.y); r[6]=(short)f2bf(hi.z); r[7]=(short)f2bf(hi.w);
  *(short8*)&W1s[(bn*16 + kt)*TILE + swz(row, kk)] = r;
}

// ---------------- kernel 0: qbias (R1 form — measured 9.9 us) --------------------
__global__ __launch_bounds__(256) void qbias_kernel(
    const float* __restrict__ hidden, const float* __restrict__ W2,
    const float* __restrict__ W1b, const float* __restrict__ W2b,
    float* __restrict__ qb){
  int b = blockIdx.x, h0 = blockIdx.y*64;
  int wave = threadIdx.x>>6, lane = threadIdx.x&63;
  const float* q = hidden + (size_t)(B_ + b)*D_;   // hidden[-1]
  for (int i=0;i<16;i++){
    int h = h0 + wave*16 + i;
    const float* w = W2 + (size_t)h*D_;
    float s = 0.f;
    #pragma unroll
    for (int it=0; it<4; ++it){
      int d = it*256 + lane*4;
      const float4 qq = *(const float4*)(q+d);
      const float4 ww = *(const float4*)(w+d);
      s += qq.x*ww.x + qq.y*ww.y + qq.z*ww.z + qq.w*ww.w;
    }
    #pragma unroll
    for (int off=1; off<64; off<<=1) s += __shfl_xor(s, off);
    if (lane==0) qb[b*H_ + h] = s + W1b[h] + W2b[h];
  }
}

// ---------------- kernel 1: fused score GEMM — single barrier per K-step ---------
// As[2] (32K) + Bs[3] (48K) = 80K -> 2 blocks/CU.  Per step kt:
//   GLD_B(kt+2->Bs[(kt+2)%3]) | CVT_A(kt+1->As[(kt+1)&1]) [reads regs loaded at
//   step kt-1 BEFORE this step's LOAD_A overwrites them] | LOAD_A(kt+2) |
//   COMPUTE(As[kt&1], Bs[kt%3]) | vmcnt(12)+lgkm(0) | bar
// R20/R21 bug was the PROLOGUE: CVT_A(0) ran after LOAD_A(1) had overwritten the
// single A reg buffer -> As[0]=A1. Fixed: consume A0 before issuing A1.
__global__ __launch_bounds__(256, 2) void score_gemm(
    const float* __restrict__ enc, const unsigned short* __restrict__ W1s,
    const float* __restrict__ qb, const float* __restrict__ Vw,
    float* __restrict__ score_p){
  const int id  = blockIdx.x;
  const int xcd = id & 7;
  const int j   = id >> 3;
  const int bm  = xcd*64 + (j >> 2);    // 4 same-bm blocks on same XCD (R5)
  const int bn  = j & 3;
  const int m0 = bm*BM, h0 = bn*BN;
  const int tid = threadIdx.x, lane = tid&63, wave = tid>>6;
  const int wm = (wave>>1)*64, wn = (wave&1)*64;

  __shared__ __align__(16) unsigned short As[2][TILE];   // 32 KB
  __shared__ __align__(16) unsigned short Bs[3][TILE];   // 48 KB

  f32x4 acc[4][4];
  #pragma unroll
  for (int i=0;i<4;i++)
    #pragma unroll
    for (int j2=0;j2<4;j2++)
      acc[i][j2] = (f32x4)(0.f);

  float4 aLo[4], aHi[4];   // single A reg buffer (consume-then-reload invariant!)

#define LOAD_A(KT) do{ const int kkx=(KT)*BK; \
  _Pragma("unroll") for (int i=0;i<4;i++){ \
    int c=tid+i*256; int row=c>>3, kc=(c&7)*8; \
    const float4* pa=(const float4*)(enc+(size_t)(m0+row)*D_+kkx+kc); \
    aLo[i]=pa[0]; aHi[i]=pa[1]; } }while(0)

#define GLD_B(KT,P) do{ const unsigned short* bsrc=W1s+(size_t)(bn*16+(KT))*TILE; \
  _Pragma("unroll") for (int i=0;i<4;i++){ \
    __builtin_amdgcn_global_load_lds( \
      (const __attribute__((address_space(1))) unsigned int*)(bsrc+i*2048+tid*8), \
      (__attribute__((address_space(3))) unsigned int*)&Bs[P][i*2048+tid*8], 16,0,0); } }while(0)

#define CVT_A(QW) do{ \
  _Pragma("unroll") for (int i=0;i<4;i++){ \
    int c=tid+i*256; int row=c>>3, kc=(c&7)*8; short8 av; \
    av[0]=(short)f2bf(aLo[i].x); av[1]=(short)f2bf(aLo[i].y); \
    av[2]=(short)f2bf(aLo[i].z); av[3]=(short)f2bf(aLo[i].w); \
    av[4]=(short)f2bf(aHi[i].x); av[5]=(short)f2bf(aHi[i].y); \
    av[6]=(short)f2bf(aHi[i].z); av[7]=(short)f2bf(aHi[i].w); \
    *(short8*)&As[QW][swz(row,kc)] = av; } }while(0)

#define COMPUTE(Q,P) do{ \
  _Pragma("unroll") for (int kh=0; kh<2; ++kh){ \
    const int kb = kh*32 + (lane>>4)*8; \
    short8 af[4], bf[4]; \
    _Pragma("unroll") for (int mi=0;mi<4;mi++){ \
      int row=wm+mi*16+(lane&15); af[mi]=*(const short8*)&As[Q][swz(row,kb)]; } \
    _Pragma("unroll") for (int ni=0;ni<4;ni++){ \
      int row=wn+ni*16+(lane&15); bf[ni]=*(const short8*)&Bs[P][swz(row,kb)]; } \
    _Pragma("unroll") for (int mi=0;mi<4;mi++) \
      _Pragma("unroll") for (int ni=0;ni<4;ni++) \
        acc[mi][ni]=__builtin_amdgcn_mfma_f32_16x16x32_bf16(af[mi],bf[ni],acc[mi][ni],0,0,0); \
  } }while(0)

#define SB() __builtin_amdgcn_sched_barrier(0)
#define WAITV_BAR(N) do{ \
  asm volatile("s_waitcnt vmcnt(" #N ") lgkmcnt(0)" ::: "memory"); \
  __builtin_amdgcn_s_barrier(); }while(0)

// One K-step.  S2=(KT+2)%3, QW=(KT+1)&1, QR=KT&1, PR=KT%3 — all literals.
// vmcnt(12) = keep this step's GLD_B(4)+LOAD_A(8); drains B(KT+1), A(KT+1).
#define STEP(KT, S2, QW, QR, PR) do{ \
  GLD_B((KT)+2, S2);  SB(); \
  CVT_A(QW);          /* reads A(KT+1) loaded last step, BEFORE overwrite */ \
  LOAD_A((KT)+2);     SB(); \
  COMPUTE(QR, PR); \
  WAITV_BAR(12); }while(0)

  // ---- prologue (R20/R21 bug fixed: consume A0 before loading A1)
  GLD_B(0,0);  SB();
  LOAD_A(0);   SB();
  CVT_A(0);                 // As[0]=A0 (auto-wait drains B0+A0)
  GLD_B(1,1);  SB();
  LOAD_A(1);   SB();        // in flight: B1:4 + A1:8 = 12
  WAITV_BAR(12);

  // ---- steady: fully static slots (As period 2, Bs period 3)
  STEP(0,  2, 1, 0, 0);
  STEP(1,  0, 0, 1, 1);
  STEP(2,  1, 1, 0, 2);
  STEP(3,  2, 0, 1, 0);
  STEP(4,  0, 1, 0, 1);
  STEP(5,  1, 0, 1, 2);
  STEP(6,  2, 1, 0, 0);
  STEP(7,  0, 0, 1, 1);
  STEP(8,  1, 1, 0, 2);
  STEP(9,  2, 0, 1, 0);
  STEP(10, 0, 1, 0, 1);
  STEP(11, 1, 0, 1, 2);
  STEP(12, 2, 1, 0, 0);
  STEP(13, 0, 0, 1, 1);
  // ---- step 14: in-flight B15:4, A15:8.  CVT A15; compute A14/B14; drain all.
  CVT_A(1);                 // As[1]=A15 (auto-wait A15)
  COMPUTE(0, 2);            // A14 (As[0]), B14 (Bs[2])
  WAITV_BAR(0);             // B15 landed in Bs[0]; As[1] visible
  // ---- step 15
  COMPUTE(1, 0);            // A15 (As[1]), B15 (Bs[0])

  // ---- epilogue: fast-tanh + V_w reduce -> per-bn partial score ----------------
  const int bidx = m0 >> 11;
  float qv[4], vwv[4];
  #pragma unroll
  for (int ni=0;ni<4;ni++){
    int h = h0 + wn + ni*16 + (lane&15);
    qv[ni]  = qb[bidx*H_ + h];
    vwv[ni] = Vw[h];
  }
  __builtin_amdgcn_s_barrier();      // all step-15 LDS reads done before psum alias
  float* psum = (float*)&As[0][0];   // 4*128 f32 = 2 KB
  #pragma unroll
  for (int mi=0;mi<4;mi++){
    #pragma unroll
    for (int r=0;r<4;r++){
      float s = 0.f;
      #pragma unroll
      for (int ni=0;ni<4;ni++) s += fast_tanh(acc[mi][ni][r] + qv[ni]) * vwv[ni];
      s += __shfl_xor(s,1); s += __shfl_xor(s,2);
      s += __shfl_xor(s,4); s += __shfl_xor(s,8);
      if ((lane&15)==0){
        int m = wm + mi*16 + ((lane>>4)<<2) + r;
        psum[wave*BM + m] = s;
      }
    }
  }
  __syncthreads();
  if (tid < BM){
    int w0 = (tid>>6)*2;
    score_p[(size_t)bn*M_ + m0 + tid] = psum[w0*BM + tid] + psum[(w0+1)*BM + tid];
  }
}

// ---------------- kernel 2: masked softmax over S (sums 4 bn partials) -----------
__global__ __launch_bounds__(256) void softmax_kernel(
    const float* __restrict__ score_p, const int* __restrict__ mask,
    float* __restrict__ attn){
  int b = blockIdx.x, tid = threadIdx.x;
  int wave = tid>>6, lane = tid&63;
  __shared__ float red[8];
  float v[8];
  float mx = -1e30f;
  #pragma unroll
  for (int i=0;i<8;i++){
    int idx = b*S_ + tid + i*256;
    float sc = score_p[idx] + score_p[M_+idx] + score_p[2*M_+idx] + score_p[3*M_+idx];
    v[i] = (mask[idx]==0) ? -1e9f : sc;
    mx = fmaxf(mx, v[i]);
  }
  #pragma unroll
  for (int off=1; off<64; off<<=1) mx = fmaxf(mx, __shfl_xor(mx, off));
  if (lane==0) red[wave] = mx;
  __syncthreads();
  mx = fmaxf(fmaxf(red[0],red[1]), fmaxf(red[2],red[3]));
  float sum = 0.f;
  #pragma unroll
  for (int i=0;i<8;i++){ v[i] = __expf(v[i]-mx); sum += v[i]; }
  #pragma unroll
  for (int off=1; off<64; off<<=1) sum += __shfl_xor(sum, off);
  if (lane==0) red[4+wave] = sum;
  __syncthreads();
  float inv = 1.f/(red[4]+red[5]+red[6]+red[7]);
  #pragma unroll
  for (int i=0;i<8;i++) attn[b*S_ + tid + i*256] = v[i]*inv;
}

// ---------------- kernel 3a: context partials (NO atomics, streaming stores) -----
__global__ __launch_bounds__(256) void context_part(
    const float* __restrict__ enc, const float* __restrict__ attn,
    float* __restrict__ ctx_p){
  int b = blockIdx.x, sc = blockIdx.y;        // 32 s-chunks of 64 rows
  int s0 = sc*64;
  int d4 = threadIdx.x*4;
  const float* ep = enc + ((size_t)b*S_ + s0)*D_ + d4;
  const float* ap = attn + b*S_ + s0;
  float4 a0 = make_float4(0.f,0.f,0.f,0.f);
  float4 a1 = make_float4(0.f,0.f,0.f,0.f);
  #pragma unroll 4
  for (int i=0;i<64;i+=2){
    float w0 = ap[i], w1 = ap[i+1];
    float4 e0 = *(const float4*)(ep + (size_t)i*D_);
    float4 e1 = *(const float4*)(ep + (size_t)(i+1)*D_);
    a0.x = fmaf(w0, e0.x, a0.x); a0.y = fmaf(w0, e0.y, a0.y);
    a0.z = fmaf(w0, e0.z, a0.z); a0.w = fmaf(w0, e0.w, a0.w);
    a1.x = fmaf(w1, e1.x, a1.x); a1.y = fmaf(w1, e1.y, a1.y);
    a1.z = fmaf(w1, e1.z, a1.z); a1.w = fmaf(w1, e1.w, a1.w);
  }
  float4 t = make_float4(a0.x+a1.x, a0.y+a1.y, a0.z+a1.z, a0.w+a1.w);
  *(float4*)(ctx_p + ((size_t)b*32 + sc)*D_ + d4) = t;
}

// ---------------- kernel 3b: reduce 32 partials -> ctx ---------------------------
__global__ __launch_bounds__(256) void context_reduce(
    const float* __restrict__ ctx_p, float* __restrict__ ctx){
  int b = blockIdx.x;
  int d4 = threadIdx.x*4;
  f32x4 s = (f32x4)(0.f);
  #pragma unroll 8
  for (int sc=0; sc<32; ++sc)
    s += *(const f32x4*)(ctx_p + ((size_t)b*32 + sc)*D_ + d4);
  *(f32x4*)(ctx + (size_t)b*D_ + d4) = s;
}

extern "C" void kernel_launch(void* const* d_in, const int* in_sizes, int n_in,
                              void* d_out, int out_size, void* d_ws, size_t ws_size,
                              hipStream_t stream){
  const float* hidden = (const float*)d_in[0];
  const float* enc    = (const float*)d_in[1];
  const int*   mask   = (const int*)d_in[2];
  const float* W1w    = (const float*)d_in[3];
  const float* W1b    = (const float*)d_in[4];
  const float* W2w    = (const float*)d_in[5];
  const float* W2b    = (const float*)d_in[6];
  const float* Vw     = (const float*)d_in[7];
  // V_b (d_in[8]) provably cancels in softmax — unused.
  float* out = (float*)d_out;

  float* qb           = (float*)d_ws;                      // 64 KB
  float* score_p      = qb + B_*H_;                        // 4*M_ f32 = 1 MB
  unsigned short* W1s = (unsigned short*)(score_p + 4*M_); // 1 MB bf16 pre-swizzled
  float* ctx_p        = (float*)(W1s + H_*D_);             // 4 MB

  convw_kernel  <<<H_*D_/8/256,     256, 0, stream>>>(W1w, W1s);
  qbias_kernel  <<<dim3(B_, H_/64), 256, 0, stream>>>(hidden, W2w, W1b, W2b, qb);
  score_gemm    <<<4*(M_/BM),       256, 0, stream>>>(enc, W1s, qb, Vw, score_p);
  softmax_kernel<<<B_,              256, 0, stream>>>(score_p, mask, out + B_*D_);
  context_part  <<<dim3(B_, 32),    256, 0, stream>>>(enc, out + B_*D_, ctx_p);
  context_reduce<<<B_,              256, 0, stream>>>(ctx_p, out);
}